// Round 4
// baseline (828.453 us; speedup 1.0000x reference)
//
#include <hip/hip_runtime.h>
#include <hip/hip_cooperative_groups.h>
#include <stdint.h>

namespace cg = cooperative_groups;

#define NB 16
#define CC 32
#define HH 224
#define WW 224
#define HWP (HH*WW)          // 50176
#define NHWP (NB*HWP)        // 802816
#define PW 226
#define PSZ (PW*PW)          // 51076 padded words per image

#define NBLK 1024
#define NTHR 256
#define TT (NBLK*NTHR)       // 262144 threads

// workspace layout (bytes)
#define OFF_S1   0u
#define OFF_S2   3268864u    // 16*51076*4
#define OFF_WP1  6537728u
#define OFF_WP2  6538880u
#define OFF_SQ1  6540032u    // 32 x u64
#define OFF_SQ2  6540288u    // 32 x u64
#define OFF_SUM1 6540544u    // 32 x i32
#define OFF_SUM2 6540672u    // 32 x i32

// ============ shared helpers ============
__device__ __forceinline__ void build_ctab(const uint32_t* __restrict__ wp, int (*Ctab)[32]) {
    for (int i = threadIdx.x; i < 512; i += 256) {
        int ty = i >> 5, oc = i & 31;
        int s = 0;
        #pragma unroll
        for (int t = 0; t < 9; ++t) {
            int dh = t / 3 - 1, dw = t % 3 - 1;
            bool pad = ((ty & 1) && dh < 0) || ((ty & 2) && dh > 0) ||
                       ((ty & 4) && dw < 0) || ((ty & 8) && dw > 0);
            if (pad) s += 32 - 2 * __popc(wp[oc * 9 + t]);
        }
        Ctab[ty][oc] = s;
    }
}

__device__ __forceinline__ void decode_px(int p, int& n, int& r, int& cw) {
    n = p / HWP;
    int rem = p - n * HWP;
    r = rem / WW;
    cw = rem - r * WW;
}

#define LOAD_TAPS(base, a)                                             \
    uint32_t a##0 = (base)[-PW - 1], a##1 = (base)[-PW], a##2 = (base)[-PW + 1], \
             a##3 = (base)[-1],      a##4 = (base)[0],   a##5 = (base)[1],       \
             a##6 = (base)[PW - 1],  a##7 = (base)[PW],  a##8 = (base)[PW + 1];

#define CONV_PC(a, wb)                                                  \
    (__popc(a##0 ^ (wb)[0]) + __popc(a##1 ^ (wb)[1]) + __popc(a##2 ^ (wb)[2]) + \
     __popc(a##3 ^ (wb)[3]) + __popc(a##4 ^ (wb)[4]) + __popc(a##5 ^ (wb)[5]) + \
     __popc(a##6 ^ (wb)[6]) + __popc(a##7 ^ (wb)[7]) + __popc(a##8 ^ (wb)[8]))

__device__ __forceinline__ void affine_from(int* g_sum, unsigned long long* g_sq,
                                            const float* __restrict__ gamma,
                                            const float* __restrict__ beta,
                                            float* aL, float* dL) {
    if (threadIdx.x < 32) {
        int c = threadIdx.x;
        int s = atomicAdd(&g_sum[c], 0);                     // coherent device-scope read
        unsigned long long q = atomicAdd(&g_sq[c], 0ULL);
        double M = (double)NHWP;
        double mean = (double)s / M;
        double ex2 = (double)(long long)q / M;
        double var = ex2 - mean * mean;
        double inv = 1.0 / sqrt(var + 1e-5);
        double aa = inv * (double)gamma[c];
        aL[c] = (float)aa;
        dL[c] = (float)((double)beta[c] - aa * mean);
    }
}

__device__ __forceinline__ void stats_phase(const uint32_t* __restrict__ sp,
                                            const uint32_t* __restrict__ wp,
                                            int* __restrict__ g_sum,
                                            unsigned long long* __restrict__ g_sq,
                                            int (*Ctab)[32], int (*ls)[32], int (*lq)[32],
                                            int t) {
    build_ctab(wp, Ctab);
    __syncthreads();
    int acc_s[32], acc_q[32];
    #pragma unroll
    for (int i = 0; i < 32; ++i) { acc_s[i] = 0; acc_q[i] = 0; }
    #pragma unroll
    for (int i = 0; i < 4; ++i) {
        int p = i * TT + t;
        if (p < NHWP) {
            int n, r, cw; decode_px(p, n, r, cw);
            const uint32_t* base = sp + (size_t)n * PSZ + (r + 1) * PW + (cw + 1);
            LOAD_TAPS(base, a)
            int ty = (r == 0 ? 1 : 0) | (r == HH - 1 ? 2 : 0) |
                     (cw == 0 ? 4 : 0) | (cw == WW - 1 ? 8 : 0);
            bool anyb = __any(ty != 0);
            #pragma unroll
            for (int oc = 0; oc < 32; ++oc) {
                const uint32_t* wb = wp + oc * 9;
                int pc = CONV_PC(a, wb);
                int c = 288 - 2 * pc;
                if (anyb) c -= Ctab[ty][oc];
                acc_s[oc] += c;
                acc_q[oc] += c * c;
            }
        }
    }
    #pragma unroll
    for (int oc = 0; oc < 32; ++oc) {
        #pragma unroll
        for (int off = 32; off > 0; off >>= 1) {
            acc_s[oc] += __shfl_xor(acc_s[oc], off, 64);
            acc_q[oc] += __shfl_xor(acc_q[oc], off, 64);
        }
    }
    int lane = threadIdx.x & 63, wid = threadIdx.x >> 6;
    if (lane == 0) {
        #pragma unroll
        for (int oc = 0; oc < 32; ++oc) { ls[wid][oc] = acc_s[oc]; lq[wid][oc] = acc_q[oc]; }
    }
    __syncthreads();
    if (threadIdx.x < 32) {
        int s = ls[0][threadIdx.x] + ls[1][threadIdx.x] + ls[2][threadIdx.x] + ls[3][threadIdx.x];
        int q = lq[0][threadIdx.x] + lq[1][threadIdx.x] + lq[2][threadIdx.x] + lq[3][threadIdx.x];
        atomicAdd(&g_sum[threadIdx.x], s);
        atomicAdd(&g_sq[threadIdx.x], (unsigned long long)(long long)q);
    }
    __syncthreads();
}

// ============ THE cooperative single kernel ============
__global__ void __launch_bounds__(256, 4)
k_coop(const float* __restrict__ x,
       const uint32_t* __restrict__ w1, const uint32_t* __restrict__ w2,
       const float* __restrict__ g1, const float* __restrict__ b1,
       const float* __restrict__ g2, const float* __restrict__ b2,
       float* __restrict__ out, char* __restrict__ ws) {
    cg::grid_group grid = cg::this_grid();
    uint32_t* s1  = (uint32_t*)(ws + OFF_S1);
    uint32_t* s2  = (uint32_t*)(ws + OFF_S2);
    uint32_t* wp1 = (uint32_t*)(ws + OFF_WP1);
    uint32_t* wp2 = (uint32_t*)(ws + OFF_WP2);
    unsigned long long* sq1 = (unsigned long long*)(ws + OFF_SQ1);
    unsigned long long* sq2 = (unsigned long long*)(ws + OFF_SQ2);
    int* sum1 = (int*)(ws + OFF_SUM1);
    int* sum2 = (int*)(ws + OFF_SUM2);

    __shared__ int Ctab[16][32];
    __shared__ float aL[32], dL[32];
    __shared__ int ls[4][32], lq[4][32];

    int t = blockIdx.x * NTHR + threadIdx.x;

    // ---- phase 0: pack weights, zero stats, zero pad borders ----
    if (t < 576) {
        const uint32_t* w = (t < 288) ? w1 : w2;
        uint32_t* o = (uint32_t*)(ws + ((t < 288) ? OFF_WP1 : OFF_WP2));
        int idx = (t < 288) ? t : t - 288;
        int oc = idx / 9, k = idx - oc * 9;
        uint32_t word = 0;
        for (int i = 0; i < 32; ++i)
            word |= (w[(oc * 32 + i) * 9 + k] >> 31) << i;
        o[idx] = word;
    } else if (t < 768) {
        ((uint32_t*)(ws + OFF_SQ1))[t - 576] = 0u;
    } else if (t >= 1024 && t < 1024 + 28800) {
        int b = t - 1024;
        uint32_t* buf = (b < 14400) ? s1 : s2;
        int bb = (b < 14400) ? b : b - 14400;
        int n = bb / 900;
        int e = bb - n * 900;
        int row, col;
        if (e < 226)      { row = 0;   col = e; }
        else if (e < 452) { row = 225; col = e - 226; }
        else { int k = e - 452; row = 1 + (k >> 1); col = (k & 1) ? 225 : 0; }
        buf[(size_t)n * PSZ + row * PW + col] = 0u;
    }

    // ---- phase 1: pack x signs into padded s1 ----
    if (t < NHWP / 4) {
        int n = t / (HWP / 4);
        int rem4 = t - n * (HWP / 4);
        int px0 = rem4 * 4;
        int r = px0 / WW;
        int cw0 = px0 - r * WW;
        const uint32_t* xp = (const uint32_t*)x + (size_t)n * CC * HWP + px0;
        uint32_t b0 = 0, b1w = 0, b2w = 0, b3 = 0;
        #pragma unroll
        for (int c = 0; c < 32; ++c) {
            uint4 v = *reinterpret_cast<const uint4*>(xp + (size_t)c * HWP);
            b0 |= (v.x >> 31) << c;
            b1w |= (v.y >> 31) << c;
            b2w |= (v.z >> 31) << c;
            b3 |= (v.w >> 31) << c;
        }
        uint32_t* op = s1 + (size_t)n * PSZ + (r + 1) * PW + (cw0 + 1);
        op[0] = b0; op[1] = b1w; op[2] = b2w; op[3] = b3;
    }

    grid.sync();

    // ---- phase 2: conv1 stats ----
    stats_phase(s1, wp1, sum1, sq1, Ctab, ls, lq, t);

    grid.sync();

    // ---- phase 3: conv1 + BN1 + sign -> s2 (Ctab still holds wp1 table) ----
    affine_from(sum1, sq1, g1, b1, aL, dL);
    __syncthreads();
    #pragma unroll
    for (int i = 0; i < 4; ++i) {
        int p = i * TT + t;
        if (p < NHWP) {
            int n, r, cw; decode_px(p, n, r, cw);
            const uint32_t* base = s1 + (size_t)n * PSZ + (r + 1) * PW + (cw + 1);
            LOAD_TAPS(base, a)
            int ty = (r == 0 ? 1 : 0) | (r == HH - 1 ? 2 : 0) |
                     (cw == 0 ? 4 : 0) | (cw == WW - 1 ? 8 : 0);
            bool anyb = __any(ty != 0);
            uint32_t word = 0;
            #pragma unroll
            for (int oc = 0; oc < 32; ++oc) {
                const uint32_t* wb = wp1 + oc * 9;
                int pc = CONV_PC(a, wb);
                int c = 288 - 2 * pc;
                if (anyb) c -= Ctab[ty][oc];
                float y = fmaf(aL[oc], (float)c, dL[oc]);
                word |= (y < 0.0f ? 1u : 0u) << oc;
            }
            s2[(size_t)n * PSZ + (r + 1) * PW + (cw + 1)] = word;
        }
    }

    grid.sync();

    // ---- phase 4: conv2 stats ----
    stats_phase(s2, wp2, sum2, sq2, Ctab, ls, lq, t);

    grid.sync();

    // ---- phase 5: conv2 + BN2 + residual -> out ----
    affine_from(sum2, sq2, g2, b2, aL, dL);
    __syncthreads();
    #pragma unroll
    for (int i = 0; i < 4; ++i) {
        int p = i * TT + t;
        if (p < NHWP) {
            int n, r, cw; decode_px(p, n, r, cw);
            int rem = r * WW + cw;
            const uint32_t* base = s2 + (size_t)n * PSZ + (r + 1) * PW + (cw + 1);
            LOAD_TAPS(base, a)
            int ty = (r == 0 ? 1 : 0) | (r == HH - 1 ? 2 : 0) |
                     (cw == 0 ? 4 : 0) | (cw == WW - 1 ? 8 : 0);
            bool anyb = __any(ty != 0);
            const float* xp = x + (size_t)n * CC * HWP + rem;
            float* op = out + (size_t)n * CC * HWP + rem;
            #pragma unroll
            for (int oc = 0; oc < 32; ++oc) {
                const uint32_t* wb = wp2 + oc * 9;
                int pc = CONV_PC(a, wb);
                int c = 288 - 2 * pc;
                if (anyb) c -= Ctab[ty][oc];
                float y = fmaf(aL[oc], (float)c, dL[oc]);
                float xv = __builtin_nontemporal_load(&xp[(size_t)oc * HWP]);
                __builtin_nontemporal_store(xv + y, &op[(size_t)oc * HWP]);
            }
        }
    }
}

// ================== fallback: R3's proven 6-kernel pipeline ==================
__global__ void __launch_bounds__(256) k_setup(const uint32_t* __restrict__ w1,
                                               const uint32_t* __restrict__ w2,
                                               char* __restrict__ ws) {
    int t = blockIdx.x * 256 + threadIdx.x;
    if (t < 576) {
        const uint32_t* w = (t < 288) ? w1 : w2;
        uint32_t* o = (uint32_t*)(ws + ((t < 288) ? OFF_WP1 : OFF_WP2));
        int idx = (t < 288) ? t : t - 288;
        int oc = idx / 9, k = idx - oc * 9;
        uint32_t word = 0;
        for (int i = 0; i < 32; ++i)
            word |= (w[(oc * 32 + i) * 9 + k] >> 31) << i;
        o[idx] = word;
    } else if (t < 768) {
        ((uint32_t*)(ws + OFF_SQ1))[t - 576] = 0u;
    } else if (t >= 1024 && t < 1024 + 28800) {
        int b = t - 1024;
        uint32_t* buf = (uint32_t*)(ws + ((b < 14400) ? OFF_S1 : OFF_S2));
        int bb = (b < 14400) ? b : b - 14400;
        int n = bb / 900;
        int e = bb - n * 900;
        int row, col;
        if (e < 226)      { row = 0;   col = e; }
        else if (e < 452) { row = 225; col = e - 226; }
        else { int k = e - 452; row = 1 + (k >> 1); col = (k & 1) ? 225 : 0; }
        buf[(size_t)n * PSZ + row * PW + col] = 0u;
    }
}

__global__ void __launch_bounds__(256) k_packx(const uint32_t* __restrict__ x,
                                               uint32_t* __restrict__ sp) {
    int t = blockIdx.x * 256 + threadIdx.x;
    int n = t / (HWP / 4);
    int rem4 = t - n * (HWP / 4);
    int px0 = rem4 * 4;
    int r = px0 / WW;
    int cw0 = px0 - r * WW;
    const uint32_t* xp = x + (size_t)n * CC * HWP + px0;
    uint32_t w0 = 0, w1 = 0, w2 = 0, w3 = 0;
    #pragma unroll
    for (int c = 0; c < 32; ++c) {
        uint4 v = *reinterpret_cast<const uint4*>(xp + (size_t)c * HWP);
        w0 |= (v.x >> 31) << c;
        w1 |= (v.y >> 31) << c;
        w2 |= (v.z >> 31) << c;
        w3 |= (v.w >> 31) << c;
    }
    uint32_t* op = sp + (size_t)n * PSZ + (r + 1) * PW + (cw0 + 1);
    op[0] = w0; op[1] = w1; op[2] = w2; op[3] = w3;
}

__global__ void __launch_bounds__(256) k_stats(const uint32_t* __restrict__ sp,
                                               const uint32_t* __restrict__ wp,
                                               int* __restrict__ g_sum,
                                               unsigned long long* __restrict__ g_sq) {
    __shared__ int Ctab[16][32];
    __shared__ int ls[4][32], lq[4][32];
    int acc_s[32], acc_q[32];
    build_ctab(wp, Ctab);
    __syncthreads();
    #pragma unroll
    for (int i = 0; i < 32; ++i) { acc_s[i] = 0; acc_q[i] = 0; }
    #pragma unroll
    for (int k = 0; k < 4; ++k) {
        int p = blockIdx.x * 1024 + k * 256 + threadIdx.x;
        int n, r, cw; decode_px(p, n, r, cw);
        const uint32_t* base = sp + (size_t)n * PSZ + (r + 1) * PW + (cw + 1);
        LOAD_TAPS(base, a)
        int ty = (r == 0 ? 1 : 0) | (r == HH - 1 ? 2 : 0) |
                 (cw == 0 ? 4 : 0) | (cw == WW - 1 ? 8 : 0);
        bool anyb = __any(ty != 0);
        #pragma unroll
        for (int oc = 0; oc < 32; ++oc) {
            const uint32_t* wb = wp + oc * 9;
            int pc = CONV_PC(a, wb);
            int c = 288 - 2 * pc;
            if (anyb) c -= Ctab[ty][oc];
            acc_s[oc] += c;
            acc_q[oc] += c * c;
        }
    }
    #pragma unroll
    for (int oc = 0; oc < 32; ++oc) {
        #pragma unroll
        for (int off = 32; off > 0; off >>= 1) {
            acc_s[oc] += __shfl_xor(acc_s[oc], off, 64);
            acc_q[oc] += __shfl_xor(acc_q[oc], off, 64);
        }
    }
    int lane = threadIdx.x & 63, wid = threadIdx.x >> 6;
    if (lane == 0) {
        #pragma unroll
        for (int oc = 0; oc < 32; ++oc) { ls[wid][oc] = acc_s[oc]; lq[wid][oc] = acc_q[oc]; }
    }
    __syncthreads();
    if (threadIdx.x < 32) {
        int s = ls[0][threadIdx.x] + ls[1][threadIdx.x] + ls[2][threadIdx.x] + ls[3][threadIdx.x];
        int q = lq[0][threadIdx.x] + lq[1][threadIdx.x] + lq[2][threadIdx.x] + lq[3][threadIdx.x];
        atomicAdd(&g_sum[threadIdx.x], s);
        atomicAdd(&g_sq[threadIdx.x], (unsigned long long)(long long)q);
    }
}

__global__ void __launch_bounds__(256) k_sign(const uint32_t* __restrict__ sp,
                                              const uint32_t* __restrict__ wp,
                                              int* __restrict__ g_sum,
                                              unsigned long long* __restrict__ g_sq,
                                              const float* __restrict__ gamma,
                                              const float* __restrict__ beta,
                                              uint32_t* __restrict__ op) {
    __shared__ int Ctab[16][32];
    __shared__ float aL[32], dL[32];
    build_ctab(wp, Ctab);
    affine_from(g_sum, g_sq, gamma, beta, aL, dL);
    __syncthreads();
    int p = blockIdx.x * 256 + threadIdx.x;
    int n, r, cw; decode_px(p, n, r, cw);
    const uint32_t* base = sp + (size_t)n * PSZ + (r + 1) * PW + (cw + 1);
    LOAD_TAPS(base, a)
    int ty = (r == 0 ? 1 : 0) | (r == HH - 1 ? 2 : 0) |
             (cw == 0 ? 4 : 0) | (cw == WW - 1 ? 8 : 0);
    bool anyb = __any(ty != 0);
    uint32_t word = 0;
    #pragma unroll
    for (int oc = 0; oc < 32; ++oc) {
        const uint32_t* wb = wp + oc * 9;
        int pc = CONV_PC(a, wb);
        int c = 288 - 2 * pc;
        if (anyb) c -= Ctab[ty][oc];
        float y = fmaf(aL[oc], (float)c, dL[oc]);
        word |= (y < 0.0f ? 1u : 0u) << oc;
    }
    op[(size_t)n * PSZ + (r + 1) * PW + (cw + 1)] = word;
}

__global__ void __launch_bounds__(256) k_res(const uint32_t* __restrict__ sp,
                                             const uint32_t* __restrict__ wp,
                                             int* __restrict__ g_sum,
                                             unsigned long long* __restrict__ g_sq,
                                             const float* __restrict__ gamma,
                                             const float* __restrict__ beta,
                                             const float* __restrict__ x,
                                             float* __restrict__ out) {
    __shared__ int Ctab[16][32];
    __shared__ float aL[32], dL[32];
    build_ctab(wp, Ctab);
    affine_from(g_sum, g_sq, gamma, beta, aL, dL);
    __syncthreads();
    int p = blockIdx.x * 256 + threadIdx.x;
    int n, r, cw; decode_px(p, n, r, cw);
    int rem = r * WW + cw;
    const uint32_t* base = sp + (size_t)n * PSZ + (r + 1) * PW + (cw + 1);
    LOAD_TAPS(base, a)
    int ty = (r == 0 ? 1 : 0) | (r == HH - 1 ? 2 : 0) |
             (cw == 0 ? 4 : 0) | (cw == WW - 1 ? 8 : 0);
    bool anyb = __any(ty != 0);
    const float* xp = x + (size_t)n * CC * HWP + rem;
    float* op = out + (size_t)n * CC * HWP + rem;
    #pragma unroll
    for (int oc = 0; oc < 32; ++oc) {
        const uint32_t* wb = wp + oc * 9;
        int pc = CONV_PC(a, wb);
        int c = 288 - 2 * pc;
        if (anyb) c -= Ctab[ty][oc];
        float y = fmaf(aL[oc], (float)c, dL[oc]);
        op[(size_t)oc * HWP] = xp[(size_t)oc * HWP] + y;
    }
}

extern "C" void kernel_launch(void* const* d_in, const int* in_sizes, int n_in,
                              void* d_out, int out_size, void* d_ws, size_t ws_size,
                              hipStream_t stream) {
    const float* x  = (const float*)d_in[0];
    const uint32_t* w1 = (const uint32_t*)d_in[1];
    const float* g1 = (const float*)d_in[2];
    const float* b1 = (const float*)d_in[3];
    const uint32_t* w2 = (const uint32_t*)d_in[4];
    const float* g2 = (const float*)d_in[5];
    const float* b2 = (const float*)d_in[6];
    float* out = (float*)d_out;
    char* ws = (char*)d_ws;

    void* kargs[] = { (void*)&x, (void*)&w1, (void*)&w2, (void*)&g1, (void*)&b1,
                      (void*)&g2, (void*)&b2, (void*)&out, (void*)&ws };
    hipError_t e = hipLaunchCooperativeKernel((void*)k_coop, dim3(NBLK), dim3(NTHR),
                                              kargs, 0, stream);
    if (e != hipSuccess) {
        (void)hipGetLastError();   // clear, use fallback pipeline
        uint32_t* s1  = (uint32_t*)(ws + OFF_S1);
        uint32_t* s2  = (uint32_t*)(ws + OFF_S2);
        uint32_t* wp1 = (uint32_t*)(ws + OFF_WP1);
        uint32_t* wp2 = (uint32_t*)(ws + OFF_WP2);
        unsigned long long* sq1 = (unsigned long long*)(ws + OFF_SQ1);
        unsigned long long* sq2 = (unsigned long long*)(ws + OFF_SQ2);
        int* sum1 = (int*)(ws + OFF_SUM1);
        int* sum2 = (int*)(ws + OFF_SUM2);
        k_setup<<<120, 256, 0, stream>>>(w1, w2, ws);
        k_packx<<<784, 256, 0, stream>>>((const uint32_t*)x, s1);
        k_stats<<<784, 256, 0, stream>>>(s1, wp1, sum1, sq1);
        k_sign<<<3136, 256, 0, stream>>>(s1, wp1, sum1, sq1, g1, b1, s2);
        k_stats<<<784, 256, 0, stream>>>(s2, wp2, sum2, sq2);
        k_res<<<3136, 256, 0, stream>>>(s2, wp2, sum2, sq2, g2, b2, x, out);
    }
}